// Round 5
// baseline (7074.242 us; speedup 1.0000x reference)
//
#include <hip/hip_runtime.h>
#include <math.h>

#define HID   256
#define SEQ   512
#define BATCH 256
#define NPRED 64
#define NOUT  3
#define KCAT  515    // 3 (x_in) + 256 (ctx) + 256 (h)
#define KPAD  544    // padded to 17 k-tiles of 32 for gates MFMA
#define NKT   17
#define GATES 1024

typedef unsigned int u32;
typedef __attribute__((ext_vector_type(8))) short bf16x8;
typedef __attribute__((ext_vector_type(4))) float f32x4;

__device__ __forceinline__ float sigmoidf_(float x) { return 1.0f / (1.0f + __expf(-x)); }
__device__ __forceinline__ float tanh_(float x)     { return 1.0f - 2.0f / (__expf(2.0f * x) + 1.0f); }

__device__ __forceinline__ unsigned short f2bf(float f) {
    union { float f; u32 u; } c; c.f = f;
    u32 u = c.u + 0x7fffu + ((c.u >> 16) & 1u);
    return (unsigned short)(u >> 16);
}
__device__ __forceinline__ float bf2f(unsigned short s) {
    union { u32 x; float f; } c; c.x = (u32)s << 16; return c.f;
}
__device__ __forceinline__ u32 pack2(float a, float b) {
    return (u32)f2bf(a) | ((u32)f2bf(b) << 16);
}
__device__ __forceinline__ float bl(u32 u) { union { u32 x; float f; } c; c.x = u << 16;        return c.f; }
__device__ __forceinline__ float bh(u32 u) { union { u32 x; float f; } c; c.x = u & 0xffff0000u; return c.f; }
__device__ __forceinline__ bf16x8 asbf(uint4 u) { union { uint4 a; bf16x8 b; } c; c.a = u; return c.b; }

// ===========================================================================
// prep_ma: MaT[k][j] = sum_m Wa[m][k]*Ua[m][j], bf16 k-quads.
// ===========================================================================
__global__ void prep_ma(const float* __restrict__ Wa, const float* __restrict__ Ua,
                        uint2* __restrict__ Ma4) {
    const int k4 = blockIdx.x, j = threadIdx.x;
    float acc[4] = {0.f, 0.f, 0.f, 0.f};
    for (int m = 0; m < HID; ++m) {
        const float ua = Ua[m * HID + j];
        #pragma unroll
        for (int q = 0; q < 4; ++q) acc[q] += Wa[m * HID + 4 * k4 + q] * ua;
    }
    Ma4[k4 * 256 + j] = make_uint2(pack2(acc[0], acc[1]), pack2(acc[2], acc[3]));
}

__global__ void prep_misc(const float* __restrict__ b_ih, const float* __restrict__ b_hh,
                          const float* __restrict__ ba, const float* __restrict__ Ua,
                          float* __restrict__ bias_g, float* __restrict__ v0) {
    const int t = threadIdx.x;
    if (t < GATES) bias_g[t] = b_ih[t] + b_hh[t];
    if (t < HID) {
        float acc = 0.f;
        for (int m = 0; m < HID; ++m) acc += ba[m] * Ua[m * HID + t];
        v0[t] = acc;
    }
}

// Wc_A[tk][tm][lane] : A[m=gate in tm-tile][k=kcat in tk-tile] (zero-pad k>=515)
__global__ void prep_wca(const float* __restrict__ W_ih, const float* __restrict__ W_hh,
                         uint4* __restrict__ WcA) {
    const int tk = blockIdx.x / 64, tm = blockIdx.x % 64;
    const int L = threadIdx.x;
    const int g = tm * 16 + (L & 15);
    const int k0 = tk * 32 + ((L >> 4) * 8);
    float f[8];
    #pragma unroll
    for (int jj = 0; jj < 8; ++jj) {
        const int kk = k0 + jj;
        f[jj] = (kk < 259) ? W_ih[g * 259 + kk]
              : (kk < KCAT) ? W_hh[g * HID + (kk - 259)] : 0.f;
    }
    WcA[((size_t)tk * 64 + tm) * 64 + L] =
        make_uint4(pack2(f[0], f[1]), pack2(f[2], f[3]),
                   pack2(f[4], f[5]), pack2(f[6], f[7]));
}

// ===========================================================================
// Register-resident decoder: one 1024-thread block per batch element.
// enc[b] (256 KB bf16) lives in registers as MFMA A-fragments for the whole
// 64-step loop: wave wv holds 16 s-tiles (half the seq, tshalf=wv&1) for one
// 32-wide h-chunk (tk=wv>>1). 16 uint4 = 64 VGPRs/lane.
// ===========================================================================
__global__ __launch_bounds__(1024)
void decoder_reg(const float* __restrict__ enc,
                 const float* __restrict__ h0, const float* __restrict__ c0,
                 const float* __restrict__ Wo, const float* __restrict__ bo,
                 const uint2* __restrict__ Ma4, const float* __restrict__ v0,
                 const uint4* __restrict__ WcA, const float* __restrict__ bias_g,
                 float* __restrict__ pred_out, float* __restrict__ hid_out,
                 float* __restrict__ attn_out)
{
    const int b  = blockIdx.x;
    const int t  = threadIdx.x;
    const int wv = t >> 6;        // 0..15
    const int L  = t & 63;
    const int j  = t & 255;
    const int ks = t >> 8;        // 0..3
    const int quad = L >> 4;      // 0..3
    const int col  = L & 15;
    const int tk     = wv >> 1;   // h-chunk 0..7 (32 h each)
    const int tshalf = wv & 1;    // s-half 0..1 (256 s each)

    __shared__ __align__(16) float s_h[HID], s_c[HID];
    __shared__ __align__(16) float s_part[4][HID];
    __shared__ __align__(16) u32   s_vq_hi[128], s_vq_lo[128];
    __shared__ __align__(16) float s_spart[8][SEQ];   // per-tk score partials
    __shared__ __align__(16) float s_scores[SEQ];
    __shared__ __align__(16) float s_wf[SEQ];
    __shared__ __align__(16) float s_cpart[2][HID];
    __shared__ __align__(16) float s_xcat[KPAD];
    __shared__ __align__(16) u32   s_xh[KPAD / 2], s_xl[KPAD / 2];
    __shared__ __align__(16) float s_gates[GATES];
    __shared__ float s_red[4], s_red2[4];

    // ---- one-time: load enc[b] into register fragments (bf16 A-layout) ----
    const float* encb = enc + (size_t)b * SEQ * HID;
    uint4 Ae[16];
    #pragma unroll
    for (int i = 0; i < 16; ++i) {
        const int s = (tshalf * 16 + i) * 16 + col;
        const float* p = encb + (size_t)s * HID + tk * 32 + quad * 8;
        const float4 f0 = *(const float4*)p;
        const float4 f1 = *(const float4*)(p + 4);
        Ae[i] = make_uint4(pack2(f0.x, f0.y), pack2(f0.z, f0.w),
                           pack2(f1.x, f1.y), pack2(f1.z, f1.w));
    }

    if (t < HID) {
        s_h[t] = h0[b * HID + t];
        s_c[t] = c0[b * HID + t];
        s_xcat[259 + t] = s_h[t];
        if (t < NOUT) s_xcat[t] = 0.0f;               // SOS
    }
    if (t < KPAD - KCAT) s_xcat[KCAT + t] = 0.0f;     // zero pad
    __syncthreads();

    float* attn_b0 = attn_out + (size_t)b * NPRED * SEQ;

    for (int n = 0; n < NPRED; ++n) {
        // ---- P1: vq = v0 + Ma^T h (VALU, bf16 Ma from L2, 4-way split-K) ----
        {
            float acc = 0.0f;
            #pragma unroll 4
            for (int qq = 0; qq < 16; ++qq) {
                const int q = ks * 16 + qq;
                const uint2 u  = Ma4[q * 256 + j];
                const float4 h4 = *(const float4*)&s_h[4 * q];
                acc += bl(u.x) * h4.x + bh(u.x) * h4.y
                     + bl(u.y) * h4.z + bh(u.y) * h4.w;
            }
            s_part[ks][j] = acc;
        }
        __syncthreads();
        if (t < 128) {   // finalize vq pairs, split bf16 hi/lo
            const int i0 = 2 * t, i1 = 2 * t + 1;
            const float va = v0[i0] + s_part[0][i0] + s_part[1][i0] + s_part[2][i0] + s_part[3][i0];
            const float vb = v0[i1] + s_part[0][i1] + s_part[1][i1] + s_part[2][i1] + s_part[3][i1];
            const unsigned short ha = f2bf(va), hb = f2bf(vb);
            s_vq_hi[t] = (u32)ha | ((u32)hb << 16);
            s_vq_lo[t] = pack2(va - bf2f(ha), vb - bf2f(hb));
        }
        __syncthreads();

        // ---- Scores: partial-k MFMA from register fragments ----
        {
            const bf16x8 Bh = asbf(*(const uint4*)&s_vq_hi[tk * 16 + quad * 4]);
            const bf16x8 Bl = asbf(*(const uint4*)&s_vq_lo[tk * 16 + quad * 4]);
            #pragma unroll
            for (int i = 0; i < 16; ++i) {
                f32x4 a = {0.f, 0.f, 0.f, 0.f};
                a = __builtin_amdgcn_mfma_f32_16x16x32_bf16(asbf(Ae[i]), Bh, a, 0, 0, 0);
                a = __builtin_amdgcn_mfma_f32_16x16x32_bf16(asbf(Ae[i]), Bl, a, 0, 0, 0);
                if (col == 0) {
                    #pragma unroll
                    for (int r = 0; r < 4; ++r)
                        s_spart[tk][(tshalf * 16 + i) * 16 + quad * 4 + r] = a[r];
                }
            }
        }
        __syncthreads();
        if (t < SEQ) {   // reduce 8 k-partials
            float sc = s_spart[0][t];
            #pragma unroll
            for (int k = 1; k < 8; ++k) sc += s_spart[k][t];
            s_scores[t] = sc;
        }
        __syncthreads();

        // ---- exact softmax (t<256 owns a score pair) ----
        float x0, x1, e0, e1;
        if (t < 256) {
            x0 = s_scores[2 * t]; x1 = s_scores[2 * t + 1];
            float mx = fmaxf(x0, x1);
            #pragma unroll
            for (int off = 32; off >= 1; off >>= 1) mx = fmaxf(mx, __shfl_xor(mx, off));
            if (L == 0) s_red[wv] = mx;
        }
        __syncthreads();
        if (t < 256) {
            const float M = fmaxf(fmaxf(s_red[0], s_red[1]), fmaxf(s_red[2], s_red[3]));
            e0 = __expf(x0 - M); e1 = __expf(x1 - M);
            float se = e0 + e1;
            #pragma unroll
            for (int off = 32; off >= 1; off >>= 1) se += __shfl_xor(se, off);
            if (L == 0) s_red2[wv] = se;
        }
        __syncthreads();
        if (t < 256) {
            const float invL = 1.0f / (s_red2[0] + s_red2[1] + s_red2[2] + s_red2[3]);
            const float w0 = e0 * invL, w1 = e1 * invL;
            ((float2*)(attn_b0 + (size_t)n * SEQ))[t] = make_float2(w0, w1);
            s_wf[2 * t] = w0; s_wf[2 * t + 1] = w1;
        }
        __syncthreads();

        // ---- ctx from register fragments (fp32 w, fp32 acc) ----
        {
            float ar[8] = {0.f, 0.f, 0.f, 0.f, 0.f, 0.f, 0.f, 0.f};
            #pragma unroll
            for (int i = 0; i < 16; ++i) {
                const float wL = s_wf[(tshalf * 16 + i) * 16 + col];
                const uint4 u = Ae[i];
                ar[0] += wL * bl(u.x); ar[1] += wL * bh(u.x);
                ar[2] += wL * bl(u.y); ar[3] += wL * bh(u.y);
                ar[4] += wL * bl(u.z); ar[5] += wL * bh(u.z);
                ar[6] += wL * bl(u.w); ar[7] += wL * bh(u.w);
            }
            #pragma unroll
            for (int off = 1; off < 16; off <<= 1) {
                #pragma unroll
                for (int q = 0; q < 8; ++q) ar[q] += __shfl_xor(ar[q], off);
            }
            if (col == 0) {
                #pragma unroll
                for (int q = 0; q < 8; ++q)
                    s_cpart[tshalf][tk * 32 + quad * 8 + q] = ar[q];
            }
        }
        __syncthreads();
        if (t < HID) s_xcat[3 + t] = s_cpart[0][t] + s_cpart[1][t];
        __syncthreads();

        // ---- pack xcat into bf16 hi/lo pairs ----
        if (t < KPAD / 2) {
            const float xa = s_xcat[2 * t], xb = s_xcat[2 * t + 1];
            const unsigned short ha = f2bf(xa), hb = f2bf(xb);
            s_xh[t] = (u32)ha | ((u32)hb << 16);
            s_xl[t] = pack2(xa - bf2f(ha), xb - bf2f(hb));
        }
        __syncthreads();

        // ---- Gates via MFMA: wave wv owns gate-tiles 4wv..4wv+3 (2 pairs) ----
        #pragma unroll
        for (int pr = 0; pr < 2; ++pr) {
            f32x4 g0 = {0.f, 0.f, 0.f, 0.f}, g1 = {0.f, 0.f, 0.f, 0.f};
            for (int tkk = 0; tkk < NKT; ++tkk) {
                const int p0 = tkk * 16 + quad * 4;
                const bf16x8 Bh2 = asbf(*(const uint4*)&s_xh[p0]);
                const bf16x8 Bl2 = asbf(*(const uint4*)&s_xl[p0]);
                const uint4* Ab = WcA + ((size_t)tkk * 64 + wv * 4 + pr * 2) * 64 + L;
                const bf16x8 A0 = asbf(Ab[0]);
                const bf16x8 A1 = asbf(Ab[64]);
                g0 = __builtin_amdgcn_mfma_f32_16x16x32_bf16(A0, Bh2, g0, 0, 0, 0);
                g0 = __builtin_amdgcn_mfma_f32_16x16x32_bf16(A0, Bl2, g0, 0, 0, 0);
                g1 = __builtin_amdgcn_mfma_f32_16x16x32_bf16(A1, Bh2, g1, 0, 0, 0);
                g1 = __builtin_amdgcn_mfma_f32_16x16x32_bf16(A1, Bl2, g1, 0, 0, 0);
            }
            if (col == 0) {
                const int r0 = quad * 4;
                #pragma unroll
                for (int r = 0; r < 4; ++r) {
                    s_gates[(wv * 4 + pr * 2    ) * 16 + r0 + r] = g0[r];
                    s_gates[(wv * 4 + pr * 2 + 1) * 16 + r0 + r] = g1[r];
                }
            }
        }
        __syncthreads();

        // ---- LSTM pointwise (unit t); gate order i,f,g,o ----
        if (t < HID) {
            const float gi = bias_g[t]       + s_gates[t];
            const float gf = bias_g[256 + t] + s_gates[256 + t];
            const float gg = bias_g[512 + t] + s_gates[512 + t];
            const float go = bias_g[768 + t] + s_gates[768 + t];
            const float cn = sigmoidf_(gf) * s_c[t] + sigmoidf_(gi) * tanh_(gg);
            const float hn = sigmoidf_(go) * tanh_(cn);
            s_c[t] = cn;
            s_h[t] = hn;
            s_xcat[259 + t] = hn;
        }
        __syncthreads();

        // ---- pred[o] = Wo[o].h + bo[o]; feedback as next x_in ----
        if (wv < NOUT) {
            const float4 w4 = *(const float4*)&Wo[wv * HID + L * 4];
            const float4 h4 = *(const float4*)&s_h[L * 4];
            float p = w4.x * h4.x + w4.y * h4.y + w4.z * h4.z + w4.w * h4.w;
            #pragma unroll
            for (int off = 32; off >= 1; off >>= 1) p += __shfl_xor(p, off);
            if (L == 0) {
                p += bo[wv];
                s_xcat[wv] = p;
                pred_out[((size_t)b * NPRED + n) * NOUT + wv] = p;
            }
        }
        __syncthreads();
    }

    if (t < HID) hid_out[b * HID + t] = s_h[t];
}

// ===========================================================================
extern "C" void kernel_launch(void* const* d_in, const int* in_sizes, int n_in,
                              void* d_out, int out_size, void* d_ws, size_t ws_size,
                              hipStream_t stream) {
    const float* enc  = (const float*)d_in[0];
    const float* h0   = (const float*)d_in[1];
    const float* c0   = (const float*)d_in[2];
    const float* Wa   = (const float*)d_in[3];
    const float* ba   = (const float*)d_in[4];
    const float* Ua   = (const float*)d_in[5];
    // d_in[6] = bua: score contribution constant over s -> softmax-invariant, dropped
    const float* W_ih = (const float*)d_in[7];
    const float* W_hh = (const float*)d_in[8];
    const float* b_ih = (const float*)d_in[9];
    const float* b_hh = (const float*)d_in[10];
    const float* Wo   = (const float*)d_in[11];
    const float* bo   = (const float*)d_in[12];

    char* ws = (char*)d_ws;
    uint4* WcA    = (uint4*)ws;  ws += (size_t)NKT * 64 * 64 * 16;   // 1,114,112
    uint2* Ma4    = (uint2*)ws;  ws += (size_t)64 * 256 * 8;         //   131,072
    float* v0     = (float*)ws;  ws += 256 * 4;
    float* bias_g = (float*)ws;  ws += GATES * 4;                    // ~1.25 MB total

    float* pred_out = (float*)d_out;                    // [B,N,3]
    float* hid_out  = pred_out + BATCH * NPRED * NOUT;  // [1,B,H]
    float* attn_out = hid_out + BATCH * HID;            // [B,N,S]

    prep_ma  <<<dim3(64),       dim3(256),  0, stream>>>(Wa, Ua, Ma4);
    prep_misc<<<dim3(1),        dim3(1024), 0, stream>>>(b_ih, b_hh, ba, Ua, bias_g, v0);
    prep_wca <<<dim3(NKT * 64), dim3(64),   0, stream>>>(W_ih, W_hh, WcA);

    decoder_reg<<<dim3(BATCH), dim3(1024), 0, stream>>>(
        enc, h0, c0, Wo, bo, Ma4, v0, WcA, bias_g,
        pred_out, hid_out, attn_out);
}

// Round 6
// 7068.475 us; speedup vs baseline: 1.0008x; 1.0008x over previous
//
#include <hip/hip_runtime.h>
#include <math.h>

#define HID   256
#define SEQ   512
#define BATCH 256
#define NPRED 64
#define NOUT  3
#define KCAT  515    // 3 (x_in) + 256 (ctx) + 256 (h)
#define KPAD  544    // padded to 17 k-tiles of 32 for gates MFMA
#define NKT   17
#define GATES 1024

typedef unsigned int u32;
typedef __attribute__((ext_vector_type(8))) short bf16x8;
typedef __attribute__((ext_vector_type(4))) float f32x4;

__device__ __forceinline__ float sigmoidf_(float x) { return 1.0f / (1.0f + __expf(-x)); }
__device__ __forceinline__ float tanh_(float x)     { return 1.0f - 2.0f / (__expf(2.0f * x) + 1.0f); }

__device__ __forceinline__ unsigned short f2bf(float f) {
    union { float f; u32 u; } c; c.f = f;
    u32 u = c.u + 0x7fffu + ((c.u >> 16) & 1u);
    return (unsigned short)(u >> 16);
}
__device__ __forceinline__ float bf2f(unsigned short s) {
    union { u32 x; float f; } c; c.x = (u32)s << 16; return c.f;
}
__device__ __forceinline__ u32 pack2(float a, float b) {
    return (u32)f2bf(a) | ((u32)f2bf(b) << 16);
}
__device__ __forceinline__ float bl(u32 u) { union { u32 x; float f; } c; c.x = u << 16;        return c.f; }
__device__ __forceinline__ float bh(u32 u) { union { u32 x; float f; } c; c.x = u & 0xffff0000u; return c.f; }
__device__ __forceinline__ bf16x8 asbf(uint4 u) { union { uint4 a; bf16x8 b; } c; c.a = u; return c.b; }

// ===========================================================================
// prep_ma: MaT[k][j] = sum_m Wa[m][k]*Ua[m][j], bf16 k-quads.
// ===========================================================================
__global__ void prep_ma(const float* __restrict__ Wa, const float* __restrict__ Ua,
                        uint2* __restrict__ Ma4) {
    const int k4 = blockIdx.x, j = threadIdx.x;
    float acc[4] = {0.f, 0.f, 0.f, 0.f};
    for (int m = 0; m < HID; ++m) {
        const float ua = Ua[m * HID + j];
        #pragma unroll
        for (int q = 0; q < 4; ++q) acc[q] += Wa[m * HID + 4 * k4 + q] * ua;
    }
    Ma4[k4 * 256 + j] = make_uint2(pack2(acc[0], acc[1]), pack2(acc[2], acc[3]));
}

__global__ void prep_misc(const float* __restrict__ b_ih, const float* __restrict__ b_hh,
                          const float* __restrict__ ba, const float* __restrict__ Ua,
                          float* __restrict__ bias_g, float* __restrict__ v0) {
    const int t = threadIdx.x;
    if (t < GATES) bias_g[t] = b_ih[t] + b_hh[t];
    if (t < HID) {
        float acc = 0.f;
        for (int m = 0; m < HID; ++m) acc += ba[m] * Ua[m * HID + t];
        v0[t] = acc;
    }
}

// Wc_A[tk][tm][lane] : A[m=gate in tm-tile][k=kcat in tk-tile] (zero-pad k>=515)
__global__ void prep_wca(const float* __restrict__ W_ih, const float* __restrict__ W_hh,
                         uint4* __restrict__ WcA) {
    const int tk = blockIdx.x / 64, tm = blockIdx.x % 64;
    const int L = threadIdx.x;
    const int g = tm * 16 + (L & 15);
    const int k0 = tk * 32 + ((L >> 4) * 8);
    float f[8];
    #pragma unroll
    for (int jj = 0; jj < 8; ++jj) {
        const int kk = k0 + jj;
        f[jj] = (kk < 259) ? W_ih[g * 259 + kk]
              : (kk < KCAT) ? W_hh[g * HID + (kk - 259)] : 0.f;
    }
    WcA[((size_t)tk * 64 + tm) * 64 + L] =
        make_uint4(pack2(f[0], f[1]), pack2(f[2], f[3]),
                   pack2(f[4], f[5]), pack2(f[6], f[7]));
}

// ===========================================================================
// Register-resident decoder: one 1024-thread block per batch element.
// enc[b] (256 KB bf16) lives in registers as MFMA A-fragments for the whole
// 64-step loop: wave wv holds 16 s-tiles (half the seq, tshalf=wv&1) for one
// 32-wide h-chunk (tk=wv>>1). 16 uint4 = 64 VGPRs/lane.
//
// __launch_bounds__(1024, 4): grid is exactly 1 block/CU (256 blocks), so
// 4 waves/EU is the real occupancy — this raises the VGPR cap to 128/lane.
// Round 5 omitted it; compiler capped at 64 VGPRs and spilled Ae[16] to
// scratch (WRITE_SIZE 33->666 MB, FETCH 13.4 GB). This is the fix.
// ===========================================================================
__global__ __launch_bounds__(1024, 4)
void decoder_reg(const float* __restrict__ enc,
                 const float* __restrict__ h0, const float* __restrict__ c0,
                 const float* __restrict__ Wo, const float* __restrict__ bo,
                 const uint2* __restrict__ Ma4, const float* __restrict__ v0,
                 const uint4* __restrict__ WcA, const float* __restrict__ bias_g,
                 float* __restrict__ pred_out, float* __restrict__ hid_out,
                 float* __restrict__ attn_out)
{
    const int b  = blockIdx.x;
    const int t  = threadIdx.x;
    const int wv = t >> 6;        // 0..15
    const int L  = t & 63;
    const int j  = t & 255;
    const int ks = t >> 8;        // 0..3
    const int quad = L >> 4;      // 0..3
    const int col  = L & 15;
    const int tk     = wv >> 1;   // h-chunk 0..7 (32 h each)
    const int tshalf = wv & 1;    // s-half 0..1 (256 s each)

    __shared__ __align__(16) float s_h[HID], s_c[HID];
    __shared__ __align__(16) float s_part[4][HID];
    __shared__ __align__(16) u32   s_vq_hi[128], s_vq_lo[128];
    __shared__ __align__(16) float s_spart[8][SEQ];   // per-tk score partials
    __shared__ __align__(16) float s_scores[SEQ];
    __shared__ __align__(16) float s_wf[SEQ];
    __shared__ __align__(16) float s_cpart[2][HID];
    __shared__ __align__(16) float s_xcat[KPAD];
    __shared__ __align__(16) u32   s_xh[KPAD / 2], s_xl[KPAD / 2];
    __shared__ __align__(16) float s_gates[GATES];
    __shared__ float s_red[4], s_red2[4];

    // ---- one-time: load enc[b] into register fragments (bf16 A-layout) ----
    const float* encb = enc + (size_t)b * SEQ * HID;
    uint4 Ae[16];
    #pragma unroll
    for (int i = 0; i < 16; ++i) {
        const int s = (tshalf * 16 + i) * 16 + col;
        const float* p = encb + (size_t)s * HID + tk * 32 + quad * 8;
        const float4 f0 = *(const float4*)p;
        const float4 f1 = *(const float4*)(p + 4);
        Ae[i] = make_uint4(pack2(f0.x, f0.y), pack2(f0.z, f0.w),
                           pack2(f1.x, f1.y), pack2(f1.z, f1.w));
    }

    if (t < HID) {
        s_h[t] = h0[b * HID + t];
        s_c[t] = c0[b * HID + t];
        s_xcat[259 + t] = s_h[t];
        if (t < NOUT) s_xcat[t] = 0.0f;               // SOS
    }
    if (t < KPAD - KCAT) s_xcat[KCAT + t] = 0.0f;     // zero pad
    __syncthreads();

    float* attn_b0 = attn_out + (size_t)b * NPRED * SEQ;

    for (int n = 0; n < NPRED; ++n) {
        // ---- P1: vq = v0 + Ma^T h (VALU, bf16 Ma from L2, 4-way split-K) ----
        {
            float acc = 0.0f;
            #pragma unroll 4
            for (int qq = 0; qq < 16; ++qq) {
                const int q = ks * 16 + qq;
                const uint2 u  = Ma4[q * 256 + j];
                const float4 h4 = *(const float4*)&s_h[4 * q];
                acc += bl(u.x) * h4.x + bh(u.x) * h4.y
                     + bl(u.y) * h4.z + bh(u.y) * h4.w;
            }
            s_part[ks][j] = acc;
        }
        __syncthreads();
        if (t < 128) {   // finalize vq pairs, split bf16 hi/lo
            const int i0 = 2 * t, i1 = 2 * t + 1;
            const float va = v0[i0] + s_part[0][i0] + s_part[1][i0] + s_part[2][i0] + s_part[3][i0];
            const float vb = v0[i1] + s_part[0][i1] + s_part[1][i1] + s_part[2][i1] + s_part[3][i1];
            const unsigned short ha = f2bf(va), hb = f2bf(vb);
            s_vq_hi[t] = (u32)ha | ((u32)hb << 16);
            s_vq_lo[t] = pack2(va - bf2f(ha), vb - bf2f(hb));
        }
        __syncthreads();

        // ---- Scores: partial-k MFMA from register fragments ----
        {
            const bf16x8 Bh = asbf(*(const uint4*)&s_vq_hi[tk * 16 + quad * 4]);
            const bf16x8 Bl = asbf(*(const uint4*)&s_vq_lo[tk * 16 + quad * 4]);
            #pragma unroll
            for (int i = 0; i < 16; ++i) {
                f32x4 a = {0.f, 0.f, 0.f, 0.f};
                a = __builtin_amdgcn_mfma_f32_16x16x32_bf16(asbf(Ae[i]), Bh, a, 0, 0, 0);
                a = __builtin_amdgcn_mfma_f32_16x16x32_bf16(asbf(Ae[i]), Bl, a, 0, 0, 0);
                if (col == 0) {
                    #pragma unroll
                    for (int r = 0; r < 4; ++r)
                        s_spart[tk][(tshalf * 16 + i) * 16 + quad * 4 + r] = a[r];
                }
            }
        }
        __syncthreads();
        if (t < SEQ) {   // reduce 8 k-partials
            float sc = s_spart[0][t];
            #pragma unroll
            for (int k = 1; k < 8; ++k) sc += s_spart[k][t];
            s_scores[t] = sc;
        }
        __syncthreads();

        // ---- exact softmax (t<256 owns a score pair) ----
        float x0, x1, e0, e1;
        if (t < 256) {
            x0 = s_scores[2 * t]; x1 = s_scores[2 * t + 1];
            float mx = fmaxf(x0, x1);
            #pragma unroll
            for (int off = 32; off >= 1; off >>= 1) mx = fmaxf(mx, __shfl_xor(mx, off));
            if (L == 0) s_red[wv] = mx;
        }
        __syncthreads();
        if (t < 256) {
            const float M = fmaxf(fmaxf(s_red[0], s_red[1]), fmaxf(s_red[2], s_red[3]));
            e0 = __expf(x0 - M); e1 = __expf(x1 - M);
            float se = e0 + e1;
            #pragma unroll
            for (int off = 32; off >= 1; off >>= 1) se += __shfl_xor(se, off);
            if (L == 0) s_red2[wv] = se;
        }
        __syncthreads();
        if (t < 256) {
            const float invL = 1.0f / (s_red2[0] + s_red2[1] + s_red2[2] + s_red2[3]);
            const float w0 = e0 * invL, w1 = e1 * invL;
            ((float2*)(attn_b0 + (size_t)n * SEQ))[t] = make_float2(w0, w1);
            s_wf[2 * t] = w0; s_wf[2 * t + 1] = w1;
        }
        __syncthreads();

        // ---- ctx from register fragments (fp32 w, fp32 acc) ----
        {
            float ar[8] = {0.f, 0.f, 0.f, 0.f, 0.f, 0.f, 0.f, 0.f};
            #pragma unroll
            for (int i = 0; i < 16; ++i) {
                const float wL = s_wf[(tshalf * 16 + i) * 16 + col];
                const uint4 u = Ae[i];
                ar[0] += wL * bl(u.x); ar[1] += wL * bh(u.x);
                ar[2] += wL * bl(u.y); ar[3] += wL * bh(u.y);
                ar[4] += wL * bl(u.z); ar[5] += wL * bh(u.z);
                ar[6] += wL * bl(u.w); ar[7] += wL * bh(u.w);
            }
            #pragma unroll
            for (int off = 1; off < 16; off <<= 1) {
                #pragma unroll
                for (int q = 0; q < 8; ++q) ar[q] += __shfl_xor(ar[q], off);
            }
            if (col == 0) {
                #pragma unroll
                for (int q = 0; q < 8; ++q)
                    s_cpart[tshalf][tk * 32 + quad * 8 + q] = ar[q];
            }
        }
        __syncthreads();
        if (t < HID) s_xcat[3 + t] = s_cpart[0][t] + s_cpart[1][t];
        __syncthreads();

        // ---- pack xcat into bf16 hi/lo pairs ----
        if (t < KPAD / 2) {
            const float xa = s_xcat[2 * t], xb = s_xcat[2 * t + 1];
            const unsigned short ha = f2bf(xa), hb = f2bf(xb);
            s_xh[t] = (u32)ha | ((u32)hb << 16);
            s_xl[t] = pack2(xa - bf2f(ha), xb - bf2f(hb));
        }
        __syncthreads();

        // ---- Gates via MFMA: wave wv owns gate-tiles 4wv..4wv+3 (2 pairs) ----
        #pragma unroll
        for (int pr = 0; pr < 2; ++pr) {
            f32x4 g0 = {0.f, 0.f, 0.f, 0.f}, g1 = {0.f, 0.f, 0.f, 0.f};
            for (int tkk = 0; tkk < NKT; ++tkk) {
                const int p0 = tkk * 16 + quad * 4;
                const bf16x8 Bh2 = asbf(*(const uint4*)&s_xh[p0]);
                const bf16x8 Bl2 = asbf(*(const uint4*)&s_xl[p0]);
                const uint4* Ab = WcA + ((size_t)tkk * 64 + wv * 4 + pr * 2) * 64 + L;
                const bf16x8 A0 = asbf(Ab[0]);
                const bf16x8 A1 = asbf(Ab[64]);
                g0 = __builtin_amdgcn_mfma_f32_16x16x32_bf16(A0, Bh2, g0, 0, 0, 0);
                g0 = __builtin_amdgcn_mfma_f32_16x16x32_bf16(A0, Bl2, g0, 0, 0, 0);
                g1 = __builtin_amdgcn_mfma_f32_16x16x32_bf16(A1, Bh2, g1, 0, 0, 0);
                g1 = __builtin_amdgcn_mfma_f32_16x16x32_bf16(A1, Bl2, g1, 0, 0, 0);
            }
            if (col == 0) {
                const int r0 = quad * 4;
                #pragma unroll
                for (int r = 0; r < 4; ++r) {
                    s_gates[(wv * 4 + pr * 2    ) * 16 + r0 + r] = g0[r];
                    s_gates[(wv * 4 + pr * 2 + 1) * 16 + r0 + r] = g1[r];
                }
            }
        }
        __syncthreads();

        // ---- LSTM pointwise (unit t); gate order i,f,g,o ----
        if (t < HID) {
            const float gi = bias_g[t]       + s_gates[t];
            const float gf = bias_g[256 + t] + s_gates[256 + t];
            const float gg = bias_g[512 + t] + s_gates[512 + t];
            const float go = bias_g[768 + t] + s_gates[768 + t];
            const float cn = sigmoidf_(gf) * s_c[t] + sigmoidf_(gi) * tanh_(gg);
            const float hn = sigmoidf_(go) * tanh_(cn);
            s_c[t] = cn;
            s_h[t] = hn;
            s_xcat[259 + t] = hn;
        }
        __syncthreads();

        // ---- pred[o] = Wo[o].h + bo[o]; feedback as next x_in ----
        if (wv < NOUT) {
            const float4 w4 = *(const float4*)&Wo[wv * HID + L * 4];
            const float4 h4 = *(const float4*)&s_h[L * 4];
            float p = w4.x * h4.x + w4.y * h4.y + w4.z * h4.z + w4.w * h4.w;
            #pragma unroll
            for (int off = 32; off >= 1; off >>= 1) p += __shfl_xor(p, off);
            if (L == 0) {
                p += bo[wv];
                s_xcat[wv] = p;
                pred_out[((size_t)b * NPRED + n) * NOUT + wv] = p;
            }
        }
        __syncthreads();
    }

    if (t < HID) hid_out[b * HID + t] = s_h[t];
}

// ===========================================================================
extern "C" void kernel_launch(void* const* d_in, const int* in_sizes, int n_in,
                              void* d_out, int out_size, void* d_ws, size_t ws_size,
                              hipStream_t stream) {
    const float* enc  = (const float*)d_in[0];
    const float* h0   = (const float*)d_in[1];
    const float* c0   = (const float*)d_in[2];
    const float* Wa   = (const float*)d_in[3];
    const float* ba   = (const float*)d_in[4];
    const float* Ua   = (const float*)d_in[5];
    // d_in[6] = bua: score contribution constant over s -> softmax-invariant, dropped
    const float* W_ih = (const float*)d_in[7];
    const float* W_hh = (const float*)d_in[8];
    const float* b_ih = (const float*)d_in[9];
    const float* b_hh = (const float*)d_in[10];
    const float* Wo   = (const float*)d_in[11];
    const float* bo   = (const float*)d_in[12];

    char* ws = (char*)d_ws;
    uint4* WcA    = (uint4*)ws;  ws += (size_t)NKT * 64 * 64 * 16;   // 1,114,112
    uint2* Ma4    = (uint2*)ws;  ws += (size_t)64 * 256 * 8;         //   131,072
    float* v0     = (float*)ws;  ws += 256 * 4;
    float* bias_g = (float*)ws;  ws += GATES * 4;                    // ~1.25 MB total

    float* pred_out = (float*)d_out;                    // [B,N,3]
    float* hid_out  = pred_out + BATCH * NPRED * NOUT;  // [1,B,H]
    float* attn_out = hid_out + BATCH * HID;            // [B,N,S]

    prep_ma  <<<dim3(64),       dim3(256),  0, stream>>>(Wa, Ua, Ma4);
    prep_misc<<<dim3(1),        dim3(1024), 0, stream>>>(b_ih, b_hh, ba, Ua, bias_g, v0);
    prep_wca <<<dim3(NKT * 64), dim3(64),   0, stream>>>(W_ih, W_hh, WcA);

    decoder_reg<<<dim3(BATCH), dim3(1024), 0, stream>>>(
        enc, h0, c0, Wo, bo, Ma4, v0, WcA, bias_g,
        pred_out, hid_out, attn_out);
}